// Round 14
// baseline (157.044 us; speedup 1.0000x reference)
//
#include <hip/hip_runtime.h>
#include <hip/hip_bf16.h>

// Chamfer loss: preds/gts [8, 3, 8192] fp32 -> scalar fp32.
//
// partial: each block owns (dir, batch, qchunk, split). Packs its 512-ref
//   slice into LDS pair-SoA (xy=(xa,xb,ya,yb), zw=(za,zb,wa,wb), w=-.5|y|^2),
//   then per query tracks max_j(dot - .5ry) with v_pk_fma_f32 (2 refs/instr):
//   3 pk_fma + 1 v_max3 per ref-PAIR per query = 2 VALU instr per pair.
//   KEY FIX vs r11: query broadcast pairs are PINNED via empty asm so the
//   compiler cannot rematerialize them with v_movs in the hot loop (r10/r11:
//   VGPR=40/64 << designed, ~2.8x instr bloat, VALUBusy stuck at 61%).
// reduce: min over 16 splits, block sum, double atomic add; last block
//   (atomic ticket) writes the float output. acc/cnt zeroed via tiny memset.

typedef float f32x2 __attribute__((ext_vector_type(2)));
typedef float f32x4 __attribute__((ext_vector_type(4)));

#define CN 8192
#define NBATCH 8
#define BQ 4096        // queries per block
#define IPT 16         // queries per thread (256 threads * 16)
#define SPLITS 16      // ref-range splits
#define RB (CN / SPLITS)   // 512 refs per block
#define NP (RB / 2)        // 256 ref-pairs per block
#define QCHUNKS (CN / BQ)  // 2

__global__ __launch_bounds__(256, 2) void chamfer_partial(
    const float* __restrict__ preds, const float* __restrict__ gts,
    float* __restrict__ partial) {
  const int bid = blockIdx.x;            // 512 blocks
  const int s     = bid & (SPLITS - 1);
  const int qc    = (bid >> 4) & (QCHUNKS - 1);
  const int batch = (bid >> 5) & (NBATCH - 1);
  const int dir   = bid >> 8;            // 0: queries=preds, 1: queries=gts

  const float* __restrict__ Q = (dir ? gts : preds) + batch * 3 * CN;
  const float* __restrict__ R = (dir ? preds : gts) + batch * 3 * CN;
  const int tid = threadIdx.x;

  // Stage + pack this block's 512-ref slice (256 pairs) into LDS.
  __shared__ f32x4 lxy[NP];   // 4KB: (xa,xb,ya,yb)
  __shared__ f32x4 lzw[NP];   // 4KB: (za,zb,wa,wb), w = -0.5*|y|^2
  {
    const int j = s * NP + tid;                       // float2 index in row
    const float2 vx = ((const float2*)R)[j];          // refs 2j, 2j+1
    const float2 vy = ((const float2*)(R + CN))[j];
    const float2 vz = ((const float2*)(R + 2 * CN))[j];
    const float w0 = -0.5f * fmaf(vx.x, vx.x, fmaf(vy.x, vy.x, vz.x * vz.x));
    const float w1 = -0.5f * fmaf(vx.y, vx.y, fmaf(vy.y, vy.y, vz.y * vz.y));
    lxy[tid] = (f32x4){vx.x, vx.y, vy.x, vy.y};
    lzw[tid] = (f32x4){vz.x, vz.y, w0, w1};
  }

  // Queries: broadcast each coord into a float2 pair, then PIN the pairs so
  // the compiler keeps them in VGPRs instead of rebuilding them per use.
  f32x2 bx[IPT], by[IPT], bz[IPT];
  float mm[IPT];
#pragma unroll
  for (int k = 0; k < IPT; ++k) {
    const int q = qc * BQ + k * 256 + tid;
    const float a0 = Q[q], a1 = Q[CN + q], a2 = Q[2 * CN + q];
    bx[k] = (f32x2){a0, a0};
    by[k] = (f32x2){a1, a1};
    bz[k] = (f32x2){a2, a2};
    mm[k] = -INFINITY;   // tracks max_j (dot - 0.5*ry)
  }
#pragma unroll
  for (int k = 0; k < IPT; ++k) {
    asm("" : "+v"(bx[k]), "+v"(by[k]), "+v"(bz[k]));   // pin (no code emitted)
  }
  __syncthreads();

  // Rotating prefetch: loads for p+1 issued before compute of p.
  f32x4 xy = lxy[0], zw = lzw[0];
#pragma unroll 2
  for (int p = 0; p < NP; ++p) {
    const f32x4 nxy = lxy[(p + 1) & (NP - 1)];   // wrap read is harmless
    const f32x4 nzw = lzw[(p + 1) & (NP - 1)];
    const f32x2 X2 = xy.lo, Y2 = xy.hi, Z2 = zw.lo, W2 = zw.hi;
#pragma unroll
    for (int k = 0; k < IPT; ++k) {
      f32x2 t;
      asm("v_pk_fma_f32 %0, %1, %2, %3"
          : "=v"(t) : "v"(bz[k]), "v"(Z2), "v"(W2));
      asm("v_pk_fma_f32 %0, %1, %2, %0"
          : "+v"(t) : "v"(by[k]), "v"(Y2));
      asm("v_pk_fma_f32 %0, %1, %2, %0"
          : "+v"(t) : "v"(bx[k]), "v"(X2));
      asm("v_max3_f32 %0, %0, %1, %2"
          : "+v"(mm[k]) : "v"(t.x), "v"(t.y));
    }
    xy = nxy; zw = nzw;
  }

  // partial = rx + min_j(ry - 2dot) = rx - 2*mm  (rx recomputed from pins)
  float* __restrict__ P =
      partial +
      (size_t)(((dir * NBATCH + batch) * QCHUNKS + qc) * SPLITS + s) * BQ;
#pragma unroll
  for (int k = 0; k < IPT; ++k) {
    const float rx =
        fmaf(bx[k].x, bx[k].x, fmaf(by[k].x, by[k].x, bz[k].x * bz[k].x));
    P[k * 256 + tid] = fmaf(-2.0f, mm[k], rx);
  }
}

__global__ __launch_bounds__(256) void chamfer_reduce(
    const float* __restrict__ partial, double* __restrict__ acc,
    unsigned* __restrict__ cnt, float* __restrict__ out) {
  const int tid = threadIdx.x;
  const int g = blockIdx.x * 256 + tid;   // 131072 queries
  const int qlocal = g & (BQ - 1);
  const int grp = g >> 12;                // (dir*8+batch)*QCHUNKS+qc, 0..31

  const float* __restrict__ P = partial + (size_t)grp * (SPLITS * BQ) + qlocal;
  float m = P[0];
#pragma unroll
  for (int s2 = 1; s2 < SPLITS; ++s2) m = fminf(m, P[s2 * BQ]);

  float v = m;
#pragma unroll
  for (int off = 32; off > 0; off >>= 1) v += __shfl_down(v, off, 64);

  __shared__ float wsum[4];
  if ((tid & 63) == 0) wsum[tid >> 6] = v;
  __syncthreads();
  if (tid == 0) {
    atomicAdd(acc, (double)(wsum[0] + wsum[1] + wsum[2] + wsum[3]));
    __threadfence();
    const unsigned t = atomicAdd(cnt, 1u);
    if (t == gridDim.x - 1) {
      const double total = atomicAdd(acc, 0.0);
      out[0] = (float)total;
    }
  }
}

extern "C" void kernel_launch(void* const* d_in, const int* in_sizes, int n_in,
                              void* d_out, int out_size, void* d_ws, size_t ws_size,
                              hipStream_t stream) {
  const float* preds = (const float*)d_in[0];
  const float* gts   = (const float*)d_in[1];

  double*   acc     = (double*)d_ws;
  unsigned* cnt     = (unsigned*)((char*)d_ws + 8);
  float*    partial = (float*)((char*)d_ws + 256);   // 8.4MB

  hipMemsetAsync(d_ws, 0, 12, stream);   // zero acc + cnt
  chamfer_partial<<<512, 256, 0, stream>>>(preds, gts, partial);
  chamfer_reduce<<<512, 256, 0, stream>>>(partial, acc, cnt, (float*)d_out);
}

// Round 16
// 153.391 us; speedup vs baseline: 1.0238x; 1.0238x over previous
//
#include <hip/hip_runtime.h>
#include <hip/hip_bf16.h>

// Chamfer loss: preds/gts [8, 3, 8192] fp32 -> scalar fp32.
//
// partial: block owns (dir,batch,qchunk,split). 512-ref slice in LDS as
//   (x,y),(z,w=-.5|y|^2) f32x2 pairs. Inner loop: 2 QUERIES per packed op
//   via v_pk_fma_f32 with op_sel broadcasting the ref scalar to both halves
//   -> query regs hold natural loaded float2s (NO duplicated values for the
//   allocator to shrink; r10-r14's duplicated-pair designs all collapsed to
//   VGPR<=64 with ~2x instr bloat). 2 refs/iter merged with v_max3:
//   2.0 VALU instr per (query,ref) pair.
// reduce: min over 16 splits, block sum, double atomic add; last block
//   (atomic ticket) writes the float output. acc/cnt zeroed via tiny memset.

typedef float f32x2 __attribute__((ext_vector_type(2)));

#define CN 8192
#define NBATCH 8
#define BQ 4096        // queries per block
#define NQP 8          // query PAIRS per thread (16 queries)
#define SPLITS 16      // ref-range splits
#define RB 512         // refs per block
#define QCHUNKS 2

__global__ __launch_bounds__(256, 2) void chamfer_partial(
    const float* __restrict__ preds, const float* __restrict__ gts,
    float* __restrict__ partial) {
  const int bid = blockIdx.x;            // 512 blocks
  const int s     = bid & (SPLITS - 1);
  const int qc    = (bid >> 4) & (QCHUNKS - 1);
  const int batch = (bid >> 5) & (NBATCH - 1);
  const int dir   = bid >> 8;            // 0: queries=preds, 1: queries=gts

  const float* __restrict__ Q = (dir ? gts : preds) + batch * 3 * CN;
  const float* __restrict__ R = (dir ? preds : gts) + batch * 3 * CN;
  const int tid = threadIdx.x;

  // Stage 512 refs: L01=(x,y), L23=(z, w=-0.5*|y|^2).
  __shared__ f32x2 L01[RB];   // 4KB
  __shared__ f32x2 L23[RB];   // 4KB
  {
    const int j = s * 256 + tid;                      // float2 idx in row
    const float2 vx = ((const float2*)R)[j];          // refs 2j, 2j+1
    const float2 vy = ((const float2*)(R + CN))[j];
    const float2 vz = ((const float2*)(R + 2 * CN))[j];
    const float w0 = -0.5f * fmaf(vx.x, vx.x, fmaf(vy.x, vy.x, vz.x * vz.x));
    const float w1 = -0.5f * fmaf(vx.y, vx.y, fmaf(vy.y, vy.y, vz.y * vz.y));
    L01[2 * tid]     = (f32x2){vx.x, vy.x};
    L23[2 * tid]     = (f32x2){vz.x, w0};
    L01[2 * tid + 1] = (f32x2){vx.y, vy.y};
    L23[2 * tid + 1] = (f32x2){vz.y, w1};
  }

  // Query pairs: thread owns queries {2j, 2j+1}, j = qc*2048 + tid + 256m.
  // Each coord pair is ONE float2 load - distinct values, no duplication.
  f32x2 qx[NQP], qy[NQP], qz[NQP];
  float m0[NQP], m1[NQP];
#pragma unroll
  for (int m = 0; m < NQP; ++m) {
    const int j = qc * (BQ / 2) + tid + 256 * m;
    qx[m] = ((const f32x2*)Q)[j];
    qy[m] = ((const f32x2*)(Q + CN))[j];
    qz[m] = ((const f32x2*)(Q + 2 * CN))[j];
    m0[m] = -INFINITY;    // max_j (dot(q0,y) - 0.5*ry)
    m1[m] = -INFINITY;    // max_j (dot(q1,y) - 0.5*ry)
  }
  __syncthreads();

  // Rotating prefetch, 2 refs (A,B) per iteration.
  f32x2 a01 = L01[0], a23 = L23[0], b01 = L01[1], b23 = L23[1];
#pragma unroll 2
  for (int p = 0; p < RB / 2; ++p) {
    const int nj = (2 * p + 2) & (RB - 1);   // wrap read harmless
    const f32x2 na01 = L01[nj],     na23 = L23[nj];
    const f32x2 nb01 = L01[nj + 1], nb23 = L23[nj + 1];
#pragma unroll
    for (int m = 0; m < NQP; ++m) {
      f32x2 tA, tB;
      // t = { qz0*z + w, qz1*z + w }  (z = r23.lo bcast, w = r23.hi bcast)
      asm("v_pk_fma_f32 %0, %1, %2, %2 op_sel:[0,0,1] op_sel_hi:[1,0,1]"
          : "=v"(tA) : "v"(qz[m]), "v"(a23));
      // t += qy * y   (y = r01.hi bcast)
      asm("v_pk_fma_f32 %0, %1, %2, %0 op_sel:[0,1,0] op_sel_hi:[1,1,1]"
          : "+v"(tA) : "v"(qy[m]), "v"(a01));
      // t += qx * x   (x = r01.lo bcast)
      asm("v_pk_fma_f32 %0, %1, %2, %0 op_sel:[0,0,0] op_sel_hi:[1,0,1]"
          : "+v"(tA) : "v"(qx[m]), "v"(a01));
      asm("v_pk_fma_f32 %0, %1, %2, %2 op_sel:[0,0,1] op_sel_hi:[1,0,1]"
          : "=v"(tB) : "v"(qz[m]), "v"(b23));
      asm("v_pk_fma_f32 %0, %1, %2, %0 op_sel:[0,1,0] op_sel_hi:[1,1,1]"
          : "+v"(tB) : "v"(qy[m]), "v"(b01));
      asm("v_pk_fma_f32 %0, %1, %2, %0 op_sel:[0,0,0] op_sel_hi:[1,0,1]"
          : "+v"(tB) : "v"(qx[m]), "v"(b01));
      asm("v_max3_f32 %0, %0, %1, %2"
          : "+v"(m0[m]) : "v"(tA.x), "v"(tB.x));
      asm("v_max3_f32 %0, %0, %1, %2"
          : "+v"(m1[m]) : "v"(tA.y), "v"(tB.y));
    }
    a01 = na01; a23 = na23; b01 = nb01; b23 = nb23;
  }

  // partial = rx + min_j(ry - 2dot) = rx - 2*m
  float* __restrict__ P =
      partial +
      (size_t)(((dir * NBATCH + batch) * QCHUNKS + qc) * SPLITS + s) * BQ;
#pragma unroll
  for (int m = 0; m < NQP; ++m) {
    const float rx0 =
        fmaf(qx[m].x, qx[m].x, fmaf(qy[m].x, qy[m].x, qz[m].x * qz[m].x));
    const float rx1 =
        fmaf(qx[m].y, qx[m].y, fmaf(qy[m].y, qy[m].y, qz[m].y * qz[m].y));
    ((float2*)P)[tid + 256 * m] =
        make_float2(fmaf(-2.0f, m0[m], rx0), fmaf(-2.0f, m1[m], rx1));
  }
}

__global__ __launch_bounds__(256) void chamfer_reduce(
    const float* __restrict__ partial, double* __restrict__ acc,
    unsigned* __restrict__ cnt, float* __restrict__ out) {
  const int tid = threadIdx.x;
  const int g = blockIdx.x * 256 + tid;   // 131072 queries
  const int qlocal = g & (BQ - 1);
  const int grp = g >> 12;                // (dir*8+batch)*QCHUNKS+qc, 0..31

  const float* __restrict__ P = partial + (size_t)grp * (SPLITS * BQ) + qlocal;
  float m = P[0];
#pragma unroll
  for (int s2 = 1; s2 < SPLITS; ++s2) m = fminf(m, P[s2 * BQ]);

  float v = m;
#pragma unroll
  for (int off = 32; off > 0; off >>= 1) v += __shfl_down(v, off, 64);

  __shared__ float wsum[4];
  if ((tid & 63) == 0) wsum[tid >> 6] = v;
  __syncthreads();
  if (tid == 0) {
    atomicAdd(acc, (double)(wsum[0] + wsum[1] + wsum[2] + wsum[3]));
    __threadfence();
    const unsigned t = atomicAdd(cnt, 1u);
    if (t == gridDim.x - 1) {
      const double total = atomicAdd(acc, 0.0);
      out[0] = (float)total;
    }
  }
}

extern "C" void kernel_launch(void* const* d_in, const int* in_sizes, int n_in,
                              void* d_out, int out_size, void* d_ws, size_t ws_size,
                              hipStream_t stream) {
  const float* preds = (const float*)d_in[0];
  const float* gts   = (const float*)d_in[1];

  double*   acc     = (double*)d_ws;
  unsigned* cnt     = (unsigned*)((char*)d_ws + 8);
  float*    partial = (float*)((char*)d_ws + 256);   // 8.4MB

  hipMemsetAsync(d_ws, 0, 12, stream);   // zero acc + cnt
  chamfer_partial<<<512, 256, 0, stream>>>(preds, gts, partial);
  chamfer_reduce<<<512, 256, 0, stream>>>(partial, acc, cnt, (float*)d_out);
}